// Round 1
// 174.298 us; speedup vs baseline: 1.0065x; 1.0065x over previous
//
#include <hip/hip_runtime.h>

typedef __attribute__((ext_vector_type(8))) __bf16 bf16x8;
typedef __attribute__((ext_vector_type(4))) __bf16 bf16x4;
typedef __attribute__((ext_vector_type(4))) float f32x4;

// async global->LDS, 16B per lane; lds base must be wave-uniform (lane i
// lands at base + i*16)  [m97/m104 semantics]
__device__ __forceinline__ void async_copy16(const void* g, void* l) {
    __builtin_amdgcn_global_load_lds(
        (const __attribute__((address_space(1))) void*)g,
        (__attribute__((address_space(3))) void*)l, 16, 0, 0);
}

// ---------------------------------------------------------------------------
// Fused prep: [0,2048) cast x fp32->bf16; [2048,5120) transpose w_attn;
// [5120,6144) transpose w_proj. Block-uniform branching.
// ---------------------------------------------------------------------------
__global__ __launch_bounds__(256) void prep_k(
    const float* __restrict__ x, __bf16* __restrict__ xb,
    const float* __restrict__ wa, __bf16* __restrict__ wAt,
    const float* __restrict__ wp, __bf16* __restrict__ wPt)
{
    __shared__ float tile[32][33];
    const int bx = blockIdx.x;
    if (bx < 2048) {
        size_t i = ((size_t)bx * 256 + threadIdx.x) * 8;
        float4 a = *(const float4*)&x[i];
        float4 b = *(const float4*)&x[i + 4];
        bf16x8 o;
        o[0] = (__bf16)a.x; o[1] = (__bf16)a.y; o[2] = (__bf16)a.z; o[3] = (__bf16)a.w;
        o[4] = (__bf16)b.x; o[5] = (__bf16)b.y; o[6] = (__bf16)b.z; o[7] = (__bf16)b.w;
        *(bf16x8*)&xb[i] = o;
        return;
    }
    const float* src; __bf16* dst; int R, C, c0, r0;
    if (bx < 5120) {
        int id = bx - 2048;
        src = wa; dst = wAt; R = 1024; C = 3072;
        c0 = (id % 96) * 32; r0 = (id / 96) * 32;
    } else {
        int id = bx - 5120;
        src = wp; dst = wPt; R = 1024; C = 1024;
        c0 = (id & 31) * 32; r0 = (id >> 5) * 32;
    }
    int tx = threadIdx.x & 31, ty = threadIdx.x >> 5;  // 32 x 8
    for (int i = ty; i < 32; i += 8)
        tile[i][tx] = src[(size_t)(r0 + i) * C + (c0 + tx)];
    __syncthreads();
    for (int i = ty; i < 32; i += 8)
        dst[(size_t)(c0 + i) * R + (r0 + tx)] = (__bf16)tile[tx][i];
}

// ---------------------------------------------------------------------------
// BT-GEMM v2: C[M,Nc] = A[M,K] @ Bt[Nc,K]^T + bias[Nc]  (A,Bt bf16; bias f32)
// 128xTN tile, BK=32, 256 threads (4 waves), double-buffered one-barrier
// K-loop (r14). LDS: 128B lines, line L holds k-rows 2L,2L+1; granule c at
// pos c^(L&7) -> reads 2-way (free) [m136].
// MODE 0 (TN=128): scatter epilogue into Qh/Kh (b,h,m,d) and Vt (b,h,d,m');
//   Q scaled by log2e/8; Vt bf16x4 stores with the 64-key interleave
//   m' = tp*32+quad*8+h*4+r  (k = tp*32+h*16+quad*4+r).
// MODE 1: plain row-major fp32 output to Of.
// ---------------------------------------------------------------------------
template <int MODE, int TN>
__global__ __launch_bounds__(256) void gemm_bt(
    const __bf16* __restrict__ A, const __bf16* __restrict__ Bt,
    const float* __restrict__ bias, int K,
    __bf16* __restrict__ O0, __bf16* __restrict__ O1, __bf16* __restrict__ O2,
    float* __restrict__ Of)
{
    constexpr int NJ = TN / 32;                 // j-tiles per wave
    __shared__ __align__(16) __bf16 lds_a[2][128 * 32];
    __shared__ __align__(16) __bf16 lds_b[2][TN * 32];
    const int row0 = blockIdx.x * 128;
    const int col0 = blockIdx.y * TN;
    const int tid  = threadIdx.x;
    const int lane = tid & 63;
    const int w    = tid >> 6;
    const int wm   = (w >> 1) * 64, wn = (w & 1) * (TN / 2);
    const int quad = lane >> 4, l16 = lane & 15;

    auto stage = [&](int pb, int kb) {
#pragma unroll
        for (int t = 0; t < 2; ++t) {
            int s = t * 256 + tid;
            int L = s >> 3, c = (s & 7) ^ (L & 7);
            int row = 2 * L + (c >> 2), ch = c & 3;
            async_copy16(&A[(size_t)(row0 + row) * K + kb + ch * 8],
                         (char*)&lds_a[pb][0] + (t * 256 + w * 64) * 16);
        }
#pragma unroll
        for (int t = 0; t < TN / 64; ++t) {
            int s = t * 256 + tid;
            int L = s >> 3, c = (s & 7) ^ (L & 7);
            int row = 2 * L + (c >> 2), ch = c & 3;
            async_copy16(&Bt[(size_t)(col0 + row) * K + kb + ch * 8],
                         (char*)&lds_b[pb][0] + (t * 256 + w * 64) * 16);
        }
    };

    const int nIter = K >> 5;
    f32x4 acc[4][NJ] = {};
    stage(0, 0);
    for (int it = 0; it < nIter; ++it) {
        __syncthreads();
        if (it + 1 < nIter) stage((it + 1) & 1, (it + 1) << 5);
        const __bf16* la = &lds_a[it & 1][0];
        const __bf16* lb = &lds_b[it & 1][0];
        bf16x8 af[4], bfr[NJ];
#pragma unroll
        for (int i = 0; i < 4; ++i) {
            int r = wm + i * 16 + l16;
            int L = r >> 1, g = ((r & 1) * 4 + quad) ^ (L & 7);
            af[i] = *(const bf16x8*)&la[L * 64 + g * 8];
        }
#pragma unroll
        for (int j = 0; j < NJ; ++j) {
            int r = wn + j * 16 + l16;
            int L = r >> 1, g = ((r & 1) * 4 + quad) ^ (L & 7);
            bfr[j] = *(const bf16x8*)&lb[L * 64 + g * 8];
        }
#pragma unroll
        for (int i = 0; i < 4; ++i)
#pragma unroll
            for (int j = 0; j < NJ; ++j)
                acc[i][j] = __builtin_amdgcn_mfma_f32_16x16x32_bf16(
                    af[i], bfr[j], acc[i][j], 0, 0, 0);
    }

    // epilogue: C/D layout col = lane&15, row = quad*4 + reg  [m89/m91]
#pragma unroll
    for (int i = 0; i < 4; ++i) {
        int grow = row0 + wm + i * 16 + quad * 4;
#pragma unroll
        for (int j = 0; j < NJ; ++j) {
            int gcol = col0 + wn + j * 16 + l16;
            float bv = bias[gcol];
            if constexpr (MODE == 0) {
                int which = gcol >> 10;       // 0=q 1=k 2=v
                int n  = gcol & 1023;
                int hh = n >> 6, dd = n & 63;
                int bb = grow >> 11, mm0 = grow & 2047;
                int bhh = bb * 16 + hh;
                if (which == 2) {
                    // key-interleave within the 64-key tile (see header)
                    int w64 = mm0 & 63;
                    int mi = (mm0 & ~63) | (w64 & 32) | ((w64 & 12) << 1)
                             | ((w64 & 16) >> 2);
                    bf16x4 pk;   // 4 consecutive m' at fixed d: one 8B store
#pragma unroll
                    for (int r = 0; r < 4; ++r)
                        pk[r] = (__bf16)(acc[i][j][r] + bv);
                    *(bf16x4*)&O2[((size_t)bhh * 64 + dd) * 2048 + mi] = pk;
                } else {
#pragma unroll
                    for (int r = 0; r < 4; ++r) {
                        float v = acc[i][j][r] + bv;
                        if (which == 0)   // fold 1/sqrt(64) * log2(e)
                            O0[((size_t)bhh * 2048 + mm0 + r) * 64 + dd] =
                                (__bf16)(v * 0.18033688011112042f);
                        else
                            O1[((size_t)bhh * 2048 + mm0 + r) * 64 + dd] =
                                (__bf16)v;
                    }
                }
            } else {
#pragma unroll
                for (int r = 0; r < 4; ++r) {
                    int gr = grow + r;
                    Of[(size_t)gr * 1024 + gcol] = acc[i][j][r] + bv;
                }
            }
        }
    }
}

// ---------------------------------------------------------------------------
// Flash attention v10 (causal). Grid (32 bh, 16 y), 512 thr (8 waves),
// q-tile = 128 (wave w owns q = q0 + w*16 + l16), qt = 15 - y (longest
// first); XCD = bh & 7 -> K/V L2-resident.
// Changes vs v9 (which was VALU-issue-bound: MfmaUtil 16.7 / VALUBusy 55):
//  * each K/V 64-key tile staged once per 128 q (was per 64 q): staging
//    bytes + async-copy VALU chain halved;
//  * wave-uniform gate skips fully-masked (wave, tile) pairs: -23% active
//    wave-iterations;
//  * all LDS read offsets hoisted to precomputed regs (ko[8]/vo[8]);
//    staging uses running global pointers (+4096/+64 elems per tile);
//  * s_setprio(1) around MFMA clusters (T5, attn-verified).
// S^T = K.Q^T so P lands in-lane in MFMA operand layout. PV + row-sum use
// K=32 MFMA via the Vt key-interleave. Softmax p = exp2(s), shift-exact
// (Q pre-scaled by log2e/8; causal diag guarantees l >= 1).
// ---------------------------------------------------------------------------
__global__ __launch_bounds__(512, 4) void attn_kernel(
    const __bf16* __restrict__ Qh, const __bf16* __restrict__ Kh,
    const __bf16* __restrict__ Vt, __bf16* __restrict__ ctx)
{
    const int M = 2048, D = 64;
    const int bh = blockIdx.x;
    const int qt = 15 - blockIdx.y;
    const int b = bh >> 4, h = bh & 15;
    const int tid = threadIdx.x, lane = tid & 63, w = tid >> 6;
    const int quad = lane >> 4, l16 = lane & 15;

    const int q0 = qt * 128;
    const int nIter = 2 * qt + 2;             // 64-key tiles: 0 .. q0+127

    // [buf][0]=K tile [key][d] swizzled, [buf][1]=V tile [d][m'] swizzled
    __shared__ __align__(16) __bf16 smem[2][2][64 * 64];

    const __bf16* Qp = Qh + (size_t)bh * M * D;
    const __bf16* Kp = Kh + (size_t)bh * M * D;
    const __bf16* Vp = Vt + (size_t)bh * D * M;

    const int qw = q0 + w * 16;               // wave's q-base; lane q = qw+l16

    bf16x8 qf[2];
#pragma unroll
    for (int c = 0; c < 2; ++c)
        qf[c] = *(const bf16x8*)
            &Qp[(size_t)(qw + l16) * D + c * 32 + quad * 8];

    // ---- loop-invariant LDS read offsets (elements), kept in VGPRs ----
    int ko[8];                                // K-frag reads: [t][c]
#pragma unroll
    for (int t = 0; t < 4; ++t)
#pragma unroll
        for (int c = 0; c < 2; ++c) {
            int ch = ((c << 2) + quad) ^ (l16 & 7);
            ko[t * 2 + c] = (((t << 4) + l16) << 6) + (ch << 3);
        }
    int vo[8];                                // V-granule reads: [f][tp]
#pragma unroll
    for (int f = 0; f < 4; ++f)
#pragma unroll
        for (int tp = 0; tp < 2; ++tp) {
            int row = (f << 4) + l16;
            int g = ((tp << 2) + quad) ^ (row & 7);
            vo[f * 2 + tp] = (row << 6) + (g << 3);
        }

    // ---- staging: running per-lane global pointers, one K + one V copy
    // per wave per tile (8 waves cover the 8 KB tile) ----
    const int cch = w * 64 + lane;            // chunk 0..511, 16 B each
    const int srow = cch >> 3, sch = (cch & 7) ^ (srow & 7);
    const __bf16* kgp = &Kp[(size_t)srow * 64 + sch * 8];
    const __bf16* vgp = &Vp[(size_t)srow * M + sch * 8];
    char* const lbase = (char*)smem + w * 1024;   // wave-uniform dest base

    auto stage = [&](int pb) {
        char* d = lbase + pb * 16384;
        async_copy16(kgp, d);                 // K half: [0,8K)
        async_copy16(vgp, d + 8192);          // V half: [8K,16K)
        kgp += 4096;                          // next 64 keys (64 rows * 64 d)
        vgp += 64;                            // next 64 keys along m'
    };

    f32x4 acc2[4] = {};     // ctx^T: [f] d-tiles; col=q=l16, row=quad*4+r=d
    f32x4 acc_s = {};       // row-sums l[q]; all regs identical
    const __bf16 onev = (__bf16)1.0f;
    const bf16x8 ones8 = {onev, onev, onev, onev, onev, onev, onev, onev};

    stage(0);

    for (int it = 0; it < nIter; ++it) {
        const int kb = it << 6;
        __syncthreads();
        if (it + 1 < nIter) stage((it + 1) & 1);
        if (kb > qw + 15) continue;           // tile fully masked for wave
        const __bf16* kt = &smem[it & 1][0][0];
        const __bf16* vt = &smem[it & 1][1][0];

        // S^T[64k x 16q] = K Q^T : 4 key-tiles (rows) x 2 d-chunks
        f32x4 s[4];
        __builtin_amdgcn_s_setprio(1);
#pragma unroll
        for (int t = 0; t < 4; ++t) {
            f32x4 tt = {};
#pragma unroll
            for (int c = 0; c < 2; ++c) {
                bf16x8 kf = *(const bf16x8*)(kt + ko[t * 2 + c]);
                tt = __builtin_amdgcn_mfma_f32_16x16x32_bf16(
                    kf, qf[c], tt, 0, 0, 0);    // A=K rows, B=Q rows
            }
            s[t] = tt;
        }
        __builtin_amdgcn_s_setprio(0);
        if (kb + 63 > qw) {                  // causal boundary tile
#pragma unroll
            for (int t = 0; t < 4; ++t)
#pragma unroll
                for (int r = 0; r < 4; ++r)
                    if (kb + t * 16 + quad * 4 + r > qw + l16)
                        s[t][r] = -1e30f;
        }
        // p = exp2(s); pack two C/D tiles -> one K=32 B-frag (interleaved
        // key order matches Vt's m' layout)
        bf16x8 pf32[2];
#pragma unroll
        for (int tp = 0; tp < 2; ++tp) {
            bf16x8 pp;
#pragma unroll
            for (int r = 0; r < 4; ++r) {
                pp[r]     = (__bf16)exp2f(s[2 * tp][r]);
                pp[4 + r] = (__bf16)exp2f(s[2 * tp + 1][r]);
            }
            pf32[tp] = pp;
        }
        // ctx^T += V P (K=32): full b128 granule = A-frag; l += 1.P
        __builtin_amdgcn_s_setprio(1);
#pragma unroll
        for (int f = 0; f < 4; ++f) {
#pragma unroll
            for (int tp = 0; tp < 2; ++tp) {
                bf16x8 vv = *(const bf16x8*)(vt + vo[f * 2 + tp]);
                acc2[f] = __builtin_amdgcn_mfma_f32_16x16x32_bf16(
                    vv, pf32[tp], acc2[f], 0, 0, 0);
            }
        }
#pragma unroll
        for (int tp = 0; tp < 2; ++tp)
            acc_s = __builtin_amdgcn_mfma_f32_16x16x32_bf16(
                ones8, pf32[tp], acc_s, 0, 0, 0);
        __builtin_amdgcn_s_setprio(0);
    }

    // epilogue: divide by l, transpose ctx^T -> ctx via dead smem space
    __syncthreads();                          // all waves done with K/V LDS
    __bf16* ldsT = (__bf16*)smem;             // 128 x 72 bf16 = 18432 B
    const float rinv = 1.0f / acc_s[0];       // l[q=l16] (reg-independent)
#pragma unroll
    for (int f = 0; f < 4; ++f) {
        bf16x4 ov;
#pragma unroll
        for (int r = 0; r < 4; ++r)
            ov[r] = (__bf16)(acc2[f][r] * rinv);
        *(bf16x4*)&ldsT[(w * 16 + l16) * 72 + f * 16 + quad * 4] = ov;
    }
    __syncthreads();
    {
        int qq = tid >> 2;                    // 0..127
        int dp = (tid & 3) * 16;              // 0,16,32,48
        const __bf16* src = &ldsT[qq * 72 + dp];
        __bf16* dst = &ctx[((size_t)(b * 2048 + q0 + qq)) * 1024 + h * 64 + dp];
        *(bf16x8*)&dst[0] = *(const bf16x8*)&src[0];
        *(bf16x8*)&dst[8] = *(const bf16x8*)&src[8];
    }
}

// ---------------------------------------------------------------------------
// Workspace 24 MB:
//   ws[ 0M.. 8M): xb (bf16 x), later overwritten by ctx (attn output)
//   ws[ 8M..14M): wAt  (w_attn^T bf16)
//   ws[14M..16M): wPt  (w_proj^T bf16)
//   ws[16M..24M): Vt   [32,64,2048] bf16 (key-interleaved per 64-key tile)
// d_out doubles as scratch: Qh [0..8M), Kh [8M..16M) bf16, fully overwritten
// by the final fp32 projection (which never reads d_out).
// ---------------------------------------------------------------------------
extern "C" void kernel_launch(void* const* d_in, const int* in_sizes, int n_in,
                              void* d_out, int out_size, void* d_ws, size_t ws_size,
                              hipStream_t stream) {
    const float* x      = (const float*)d_in[0];
    const float* w_attn = (const float*)d_in[1];
    const float* w_proj = (const float*)d_in[2];
    const float* b_attn = (const float*)d_in[3];
    const float* b_proj = (const float*)d_in[4];
    float* out = (float*)d_out;

    char* ws = (char*)d_ws;
    __bf16* xb  = (__bf16*)(ws);
    __bf16* ctx = (__bf16*)(ws);                    // aliases xb (xb dead)
    __bf16* wAt = (__bf16*)(ws + 8388608);
    __bf16* wPt = (__bf16*)(ws + 14680064);
    __bf16* Vt  = (__bf16*)(ws + 16777216);
    __bf16* Qh  = (__bf16*)d_out;
    __bf16* Kh  = (__bf16*)d_out + 4194304;

    prep_k<<<6144, 256, 0, stream>>>(x, xb, w_attn, wAt, w_proj, wPt);
    gemm_bt<0, 128><<<dim3(32, 24), 256, 0, stream>>>(xb, wAt, b_attn, 1024,
                                                      Qh, Kh, Vt, nullptr);
    attn_kernel<<<dim3(32, 16), 512, 0, stream>>>(Qh, Kh, Vt, ctx);
    gemm_bt<1, 64><<<dim3(32, 16), 256, 0, stream>>>(ctx, wPt, b_proj, 1024,
                                                     nullptr, nullptr, nullptr, out);
}

// Round 2
// 172.829 us; speedup vs baseline: 1.0150x; 1.0085x over previous
//
#include <hip/hip_runtime.h>

typedef __attribute__((ext_vector_type(8))) __bf16 bf16x8;
typedef __attribute__((ext_vector_type(4))) __bf16 bf16x4;
typedef __attribute__((ext_vector_type(4))) float f32x4;

// async global->LDS, 16B per lane; lds base must be wave-uniform (lane i
// lands at base + i*16)  [m97/m104 semantics]
__device__ __forceinline__ void async_copy16(const void* g, void* l) {
    __builtin_amdgcn_global_load_lds(
        (const __attribute__((address_space(1))) void*)g,
        (__attribute__((address_space(3))) void*)l, 16, 0, 0);
}

// raw hardware exp2: one v_exp_f32, no libm fixup chain. exp2(-1e30) == 0.
__device__ __forceinline__ float fexp2(float x) {
    return __builtin_amdgcn_exp2f(x);
}

// ---------------------------------------------------------------------------
// Fused prep: [0,2048) cast x fp32->bf16; [2048,5120) transpose w_attn;
// [5120,6144) transpose w_proj. Block-uniform branching.
// ---------------------------------------------------------------------------
__global__ __launch_bounds__(256) void prep_k(
    const float* __restrict__ x, __bf16* __restrict__ xb,
    const float* __restrict__ wa, __bf16* __restrict__ wAt,
    const float* __restrict__ wp, __bf16* __restrict__ wPt)
{
    __shared__ float tile[32][33];
    const int bx = blockIdx.x;
    if (bx < 2048) {
        size_t i = ((size_t)bx * 256 + threadIdx.x) * 8;
        float4 a = *(const float4*)&x[i];
        float4 b = *(const float4*)&x[i + 4];
        bf16x8 o;
        o[0] = (__bf16)a.x; o[1] = (__bf16)a.y; o[2] = (__bf16)a.z; o[3] = (__bf16)a.w;
        o[4] = (__bf16)b.x; o[5] = (__bf16)b.y; o[6] = (__bf16)b.z; o[7] = (__bf16)b.w;
        *(bf16x8*)&xb[i] = o;
        return;
    }
    const float* src; __bf16* dst; int R, C, c0, r0;
    if (bx < 5120) {
        int id = bx - 2048;
        src = wa; dst = wAt; R = 1024; C = 3072;
        c0 = (id % 96) * 32; r0 = (id / 96) * 32;
    } else {
        int id = bx - 5120;
        src = wp; dst = wPt; R = 1024; C = 1024;
        c0 = (id & 31) * 32; r0 = (id >> 5) * 32;
    }
    int tx = threadIdx.x & 31, ty = threadIdx.x >> 5;  // 32 x 8
    for (int i = ty; i < 32; i += 8)
        tile[i][tx] = src[(size_t)(r0 + i) * C + (c0 + tx)];
    __syncthreads();
    for (int i = ty; i < 32; i += 8)
        dst[(size_t)(c0 + i) * R + (r0 + tx)] = (__bf16)tile[tx][i];
}

// ---------------------------------------------------------------------------
// BT-GEMM v2: C[M,Nc] = A[M,K] @ Bt[Nc,K]^T + bias[Nc]  (A,Bt bf16; bias f32)
// 128xTN tile, BK=32, 256 threads (4 waves), double-buffered one-barrier
// K-loop (r14). LDS: 128B lines, line L holds k-rows 2L,2L+1; granule c at
// pos c^(L&7) -> reads 2-way (free) [m136].
// MODE 0 (TN=128): scatter epilogue into Qh/Kh (b,h,m,d) and Vt (b,h,d,m');
//   Q scaled by log2e/8; Vt bf16x4 stores with the 64-key interleave
//   m' = tp*32+quad*8+h*4+r  (k = tp*32+h*16+quad*4+r).
// MODE 1: plain row-major fp32 output to Of.
// ---------------------------------------------------------------------------
template <int MODE, int TN>
__global__ __launch_bounds__(256) void gemm_bt(
    const __bf16* __restrict__ A, const __bf16* __restrict__ Bt,
    const float* __restrict__ bias, int K,
    __bf16* __restrict__ O0, __bf16* __restrict__ O1, __bf16* __restrict__ O2,
    float* __restrict__ Of)
{
    constexpr int NJ = TN / 32;                 // j-tiles per wave
    __shared__ __align__(16) __bf16 lds_a[2][128 * 32];
    __shared__ __align__(16) __bf16 lds_b[2][TN * 32];
    const int row0 = blockIdx.x * 128;
    const int col0 = blockIdx.y * TN;
    const int tid  = threadIdx.x;
    const int lane = tid & 63;
    const int w    = tid >> 6;
    const int wm   = (w >> 1) * 64, wn = (w & 1) * (TN / 2);
    const int quad = lane >> 4, l16 = lane & 15;

    auto stage = [&](int pb, int kb) {
#pragma unroll
        for (int t = 0; t < 2; ++t) {
            int s = t * 256 + tid;
            int L = s >> 3, c = (s & 7) ^ (L & 7);
            int row = 2 * L + (c >> 2), ch = c & 3;
            async_copy16(&A[(size_t)(row0 + row) * K + kb + ch * 8],
                         (char*)&lds_a[pb][0] + (t * 256 + w * 64) * 16);
        }
#pragma unroll
        for (int t = 0; t < TN / 64; ++t) {
            int s = t * 256 + tid;
            int L = s >> 3, c = (s & 7) ^ (L & 7);
            int row = 2 * L + (c >> 2), ch = c & 3;
            async_copy16(&Bt[(size_t)(col0 + row) * K + kb + ch * 8],
                         (char*)&lds_b[pb][0] + (t * 256 + w * 64) * 16);
        }
    };

    const int nIter = K >> 5;
    f32x4 acc[4][NJ] = {};
    stage(0, 0);
    for (int it = 0; it < nIter; ++it) {
        __syncthreads();
        if (it + 1 < nIter) stage((it + 1) & 1, (it + 1) << 5);
        const __bf16* la = &lds_a[it & 1][0];
        const __bf16* lb = &lds_b[it & 1][0];
        bf16x8 af[4], bfr[NJ];
#pragma unroll
        for (int i = 0; i < 4; ++i) {
            int r = wm + i * 16 + l16;
            int L = r >> 1, g = ((r & 1) * 4 + quad) ^ (L & 7);
            af[i] = *(const bf16x8*)&la[L * 64 + g * 8];
        }
#pragma unroll
        for (int j = 0; j < NJ; ++j) {
            int r = wn + j * 16 + l16;
            int L = r >> 1, g = ((r & 1) * 4 + quad) ^ (L & 7);
            bfr[j] = *(const bf16x8*)&lb[L * 64 + g * 8];
        }
#pragma unroll
        for (int i = 0; i < 4; ++i)
#pragma unroll
            for (int j = 0; j < NJ; ++j)
                acc[i][j] = __builtin_amdgcn_mfma_f32_16x16x32_bf16(
                    af[i], bfr[j], acc[i][j], 0, 0, 0);
    }

    // epilogue: C/D layout col = lane&15, row = quad*4 + reg  [m89/m91]
#pragma unroll
    for (int i = 0; i < 4; ++i) {
        int grow = row0 + wm + i * 16 + quad * 4;
#pragma unroll
        for (int j = 0; j < NJ; ++j) {
            int gcol = col0 + wn + j * 16 + l16;
            float bv = bias[gcol];
            if constexpr (MODE == 0) {
                int which = gcol >> 10;       // 0=q 1=k 2=v
                int n  = gcol & 1023;
                int hh = n >> 6, dd = n & 63;
                int bb = grow >> 11, mm0 = grow & 2047;
                int bhh = bb * 16 + hh;
                if (which == 2) {
                    // key-interleave within the 64-key tile (see header)
                    int w64 = mm0 & 63;
                    int mi = (mm0 & ~63) | (w64 & 32) | ((w64 & 12) << 1)
                             | ((w64 & 16) >> 2);
                    bf16x4 pk;   // 4 consecutive m' at fixed d: one 8B store
#pragma unroll
                    for (int r = 0; r < 4; ++r)
                        pk[r] = (__bf16)(acc[i][j][r] + bv);
                    *(bf16x4*)&O2[((size_t)bhh * 64 + dd) * 2048 + mi] = pk;
                } else {
#pragma unroll
                    for (int r = 0; r < 4; ++r) {
                        float v = acc[i][j][r] + bv;
                        if (which == 0)   // fold 1/sqrt(64) * log2(e)
                            O0[((size_t)bhh * 2048 + mm0 + r) * 64 + dd] =
                                (__bf16)(v * 0.18033688011112042f);
                        else
                            O1[((size_t)bhh * 2048 + mm0 + r) * 64 + dd] =
                                (__bf16)v;
                    }
                }
            } else {
#pragma unroll
                for (int r = 0; r < 4; ++r) {
                    int gr = grow + r;
                    Of[(size_t)gr * 1024 + gcol] = acc[i][j][r] + bv;
                }
            }
        }
    }
}

// ---------------------------------------------------------------------------
// Flash attention v11 (causal). Balanced triangle pairing: grid (32 bh, 16 y),
// 256 thr (4 waves), each block processes q-tile A (qt=y) THEN q-tile B
// (qt=31-y): (y+1) + (32-y) = 33 key-tile iterations for EVERY block ->
// perfect static balance regardless of CU assignment (v9/v10 had a ~1.4x
// tail: co-resident blocks carried 2..32 iterations).
// Softmax VALU floor cut: raw __builtin_amdgcn_exp2f (1 inst, vs libm's
// fixup chain; masked -1e30 underflows to exact 0).
// S^T = K.Q^T so P lands in-lane in MFMA operand layout. PV + row-sum use
// K=32 MFMA via the Vt key-interleave. p = exp2(s), shift-exact (Q
// pre-scaled by log2e/8; causal diag guarantees l >= 1). XCD = bh & 7 ->
// K/V L2-resident. Hoisted LDS offsets + running stage pointers + setprio.
// ---------------------------------------------------------------------------
__global__ __launch_bounds__(256) void attn_kernel(
    const __bf16* __restrict__ Qh, const __bf16* __restrict__ Kh,
    const __bf16* __restrict__ Vt, __bf16* __restrict__ ctx)
{
    const int M = 2048, D = 64;
    const int bh = blockIdx.x;
    const int y  = blockIdx.y;                // 0..15
    const int b = bh >> 4, h = bh & 15;
    const int tid = threadIdx.x, lane = tid & 63, w = tid >> 6;
    const int quad = lane >> 4, l16 = lane & 15;

    const int nA = y + 1;                     // tiles for segment A (qt = y)
    const int nT = 33;                        // nA + nB, constant by pairing
    const int qA0 = y * 64, qB0 = (31 - y) * 64;
    const int qwA = qA0 + w * 16, qwB = qB0 + w * 16;

    // [buf][0]=K tile [key][d] swizzled, [buf][1]=V tile [d][m'] swizzled
    __shared__ __align__(16) __bf16 smem[2][2][64 * 64];

    const __bf16* Qp = Qh + (size_t)bh * M * D;
    const __bf16* Kp = Kh + (size_t)bh * M * D;
    const __bf16* Vp = Vt + (size_t)bh * D * M;

    bf16x8 qfA[2], qfB[2];
#pragma unroll
    for (int c = 0; c < 2; ++c) {
        qfA[c] = *(const bf16x8*)&Qp[(size_t)(qwA + l16) * D + c * 32 + quad * 8];
        qfB[c] = *(const bf16x8*)&Qp[(size_t)(qwB + l16) * D + c * 32 + quad * 8];
    }

    // ---- loop-invariant LDS read offsets (elements), kept in VGPRs ----
    int ko[8];                                // K-frag reads: [t][c]
#pragma unroll
    for (int t = 0; t < 4; ++t)
#pragma unroll
        for (int c = 0; c < 2; ++c) {
            int ch = ((c << 2) + quad) ^ (l16 & 7);
            ko[t * 2 + c] = (((t << 4) + l16) << 6) + (ch << 3);
        }
    int vo[8];                                // V-granule reads: [f][tp]
#pragma unroll
    for (int f = 0; f < 4; ++f)
#pragma unroll
        for (int tp = 0; tp < 2; ++tp) {
            int row = (f << 4) + l16;
            int g = ((tp << 2) + quad) ^ (row & 7);
            vo[f * 2 + tp] = (row << 6) + (g << 3);
        }

    // ---- staging: 2 K-chunks + 2 V-chunks per thread per 64-key tile,
    // running per-lane global pointers (+4096 / +64 elems per tile), reset
    // to key 0 at the A->B segment switch ----
    const __bf16* kbase[2]; const __bf16* vbase[2];
    const __bf16* kg[2];    const __bf16* vg[2];
#pragma unroll
    for (int t = 0; t < 2; ++t) {
        int c = w * 128 + t * 64 + lane;      // chunk 0..511, 16 B each
        int row = c >> 3, gch = (c & 7) ^ (row & 7);
        kbase[t] = &Kp[(size_t)row * 64 + gch * 8];
        vbase[t] = &Vp[(size_t)row * M + gch * 8];
        kg[t] = kbase[t]; vg[t] = vbase[t];
    }
    char* const lbase = (char*)smem + (w * 128) * 16;  // wave-uniform

    auto stage = [&](int pb) {
        char* d = lbase + pb * 16384;
#pragma unroll
        for (int t = 0; t < 2; ++t) {
            async_copy16(kg[t], d + t * 1024);            // K half [0,8K)
            async_copy16(vg[t], d + 8192 + t * 1024);     // V half [8K,16K)
            kg[t] += 4096;                                // next 64 keys
            vg[t] += 64;
        }
    };
    auto resetPtrs = [&]() {
#pragma unroll
        for (int t = 0; t < 2; ++t) { kg[t] = kbase[t]; vg[t] = vbase[t]; }
    };

    f32x4 accA[4] = {}, accB[4] = {};  // ctx^T: col=q=l16, row=quad*4+r=d
    f32x4 acc_sA = {}, acc_sB = {};    // row-sums l[q]; all regs identical
    const __bf16 onev = (__bf16)1.0f;
    const bf16x8 ones8 = {onev, onev, onev, onev, onev, onev, onev, onev};

    // compute one 64-key tile against this wave's 16 q-rows
    auto compute = [&](const __bf16* kt, const __bf16* vt, int kb, int qw,
                       const bf16x8 (&qf)[2], f32x4 (&a2)[4], f32x4& as) {
        // S^T[64k x 16q] = K Q^T : 4 key-tiles (rows) x 2 d-chunks
        f32x4 s[4];
        __builtin_amdgcn_s_setprio(1);
#pragma unroll
        for (int t = 0; t < 4; ++t) {
            f32x4 tt = {};
#pragma unroll
            for (int c = 0; c < 2; ++c) {
                bf16x8 kf = *(const bf16x8*)(kt + ko[t * 2 + c]);
                tt = __builtin_amdgcn_mfma_f32_16x16x32_bf16(
                    kf, qf[c], tt, 0, 0, 0);    // A=K rows, B=Q rows
            }
            s[t] = tt;
        }
        __builtin_amdgcn_s_setprio(0);
        if (kb + 63 > qw) {                  // causal boundary tile
#pragma unroll
            for (int t = 0; t < 4; ++t)
#pragma unroll
                for (int r = 0; r < 4; ++r)
                    if (kb + t * 16 + quad * 4 + r > qw + l16)
                        s[t][r] = -1e30f;
        }
        // p = exp2(s); pack two C/D tiles -> one K=32 B-frag (interleaved
        // key order matches Vt's m' layout)
        bf16x8 pf[2];
#pragma unroll
        for (int tp = 0; tp < 2; ++tp) {
            bf16x8 pp;
#pragma unroll
            for (int r = 0; r < 4; ++r) {
                pp[r]     = (__bf16)fexp2(s[2 * tp][r]);
                pp[4 + r] = (__bf16)fexp2(s[2 * tp + 1][r]);
            }
            pf[tp] = pp;
        }
        // ctx^T += V P (K=32): full b128 granule = A-frag; l += 1.P
        __builtin_amdgcn_s_setprio(1);
#pragma unroll
        for (int f = 0; f < 4; ++f) {
#pragma unroll
            for (int tp = 0; tp < 2; ++tp) {
                bf16x8 vv = *(const bf16x8*)(vt + vo[f * 2 + tp]);
                a2[f] = __builtin_amdgcn_mfma_f32_16x16x32_bf16(
                    vv, pf[tp], a2[f], 0, 0, 0);
            }
        }
#pragma unroll
        for (int tp = 0; tp < 2; ++tp)
            as = __builtin_amdgcn_mfma_f32_16x16x32_bf16(
                ones8, pf[tp], as, 0, 0, 0);
        __builtin_amdgcn_s_setprio(0);
    };

    stage(0);                                 // tile 0 (segment A, key 0)
    if (nA == 1) resetPtrs();                 // next staged tile is seg B key 0

    for (int it = 0; it < nT; ++it) {
        __syncthreads();
        int nxt = it + 1;
        if (nxt < nT) {
            stage(nxt & 1);
            if (nxt + 1 == nA) resetPtrs();
        }
        const __bf16* kt = &smem[it & 1][0][0];
        const __bf16* vt = &smem[it & 1][1][0];
        if (it < nA)
            compute(kt, vt, it * 64, qwA, qfA, accA, acc_sA);
        else
            compute(kt, vt, (it - nA) * 64, qwB, qfB, accB, acc_sB);
    }

    // epilogue: divide by l, transpose ctx^T -> ctx via dead smem space.
    // Done twice (segment A then B), reusing the same 64x72 LDS buffer.
    __bf16* ldsT = (__bf16*)smem;             // 64 x 72 bf16 = 9216 B
    const int qq = tid >> 2;                  // 0..63
    const int dp = (tid & 3) * 16;            // 0,16,32,48

    __syncthreads();                          // all waves done with K/V LDS
    {
        const float rinv = 1.0f / acc_sA[0];
#pragma unroll
        for (int f = 0; f < 4; ++f) {
            bf16x4 ov;
#pragma unroll
            for (int r = 0; r < 4; ++r)
                ov[r] = (__bf16)(accA[f][r] * rinv);
            *(bf16x4*)&ldsT[(w * 16 + l16) * 72 + f * 16 + quad * 4] = ov;
        }
        __syncthreads();
        const __bf16* src = &ldsT[qq * 72 + dp];
        __bf16* dst = &ctx[((size_t)(b * 2048 + qA0 + qq)) * 1024 + h * 64 + dp];
        *(bf16x8*)&dst[0] = *(const bf16x8*)&src[0];
        *(bf16x8*)&dst[8] = *(const bf16x8*)&src[8];
    }
    __syncthreads();
    {
        const float rinv = 1.0f / acc_sB[0];
#pragma unroll
        for (int f = 0; f < 4; ++f) {
            bf16x4 ov;
#pragma unroll
            for (int r = 0; r < 4; ++r)
                ov[r] = (__bf16)(accB[f][r] * rinv);
            *(bf16x4*)&ldsT[(w * 16 + l16) * 72 + f * 16 + quad * 4] = ov;
        }
        __syncthreads();
        const __bf16* src = &ldsT[qq * 72 + dp];
        __bf16* dst = &ctx[((size_t)(b * 2048 + qB0 + qq)) * 1024 + h * 64 + dp];
        *(bf16x8*)&dst[0] = *(const bf16x8*)&src[0];
        *(bf16x8*)&dst[8] = *(const bf16x8*)&src[8];
    }
}

// ---------------------------------------------------------------------------
// Workspace 24 MB:
//   ws[ 0M.. 8M): xb (bf16 x), later overwritten by ctx (attn output)
//   ws[ 8M..14M): wAt  (w_attn^T bf16)
//   ws[14M..16M): wPt  (w_proj^T bf16)
//   ws[16M..24M): Vt   [32,64,2048] bf16 (key-interleaved per 64-key tile)
// d_out doubles as scratch: Qh [0..8M), Kh [8M..16M) bf16, fully overwritten
// by the final fp32 projection (which never reads d_out).
// ---------------------------------------------------------------------------
extern "C" void kernel_launch(void* const* d_in, const int* in_sizes, int n_in,
                              void* d_out, int out_size, void* d_ws, size_t ws_size,
                              hipStream_t stream) {
    const float* x      = (const float*)d_in[0];
    const float* w_attn = (const float*)d_in[1];
    const float* w_proj = (const float*)d_in[2];
    const float* b_attn = (const float*)d_in[3];
    const float* b_proj = (const float*)d_in[4];
    float* out = (float*)d_out;

    char* ws = (char*)d_ws;
    __bf16* xb  = (__bf16*)(ws);
    __bf16* ctx = (__bf16*)(ws);                    // aliases xb (xb dead)
    __bf16* wAt = (__bf16*)(ws + 8388608);
    __bf16* wPt = (__bf16*)(ws + 14680064);
    __bf16* Vt  = (__bf16*)(ws + 16777216);
    __bf16* Qh  = (__bf16*)d_out;
    __bf16* Kh  = (__bf16*)d_out + 4194304;

    prep_k<<<6144, 256, 0, stream>>>(x, xb, w_attn, wAt, w_proj, wPt);
    gemm_bt<0, 128><<<dim3(32, 24), 256, 0, stream>>>(xb, wAt, b_attn, 1024,
                                                      Qh, Kh, Vt, nullptr);
    attn_kernel<<<dim3(32, 16), 256, 0, stream>>>(Qh, Kh, Vt, ctx);
    gemm_bt<1, 64><<<dim3(32, 16), 256, 0, stream>>>(ctx, wPt, b_proj, 1024,
                                                     nullptr, nullptr, nullptr, out);
}